// Round 3
// baseline (1327.470 us; speedup 1.0000x reference)
//
#include <hip/hip_runtime.h>
#include <stdint.h>

typedef unsigned short u16;
typedef __bf16 bf16x8 __attribute__((ext_vector_type(8)));
typedef float f32x4 __attribute__((ext_vector_type(4)));

#define D_MODEL 2048
#define NHEADS 16
#define DK 128
#define DFF 5504
#define BB 2
#define SS 2048
#define MTOK 4096  // B*S

__device__ __forceinline__ u16 f2bf(float f){
  union { float f; uint32_t u; } v; v.f = f;
  uint32_t r = v.u + 0x7fffu + ((v.u >> 16) & 1u);
  return (u16)(r >> 16);
}
__device__ __forceinline__ float bf2f(u16 u){
  union { uint32_t u; float f; } v; v.u = ((uint32_t)u) << 16;
  return v.f;
}
__device__ __forceinline__ u16 cvt_bf16(float f){
  union { __bf16 h; u16 u; } v; v.h = (__bf16)f; return v.u;
}
__device__ __forceinline__ float fexp2(float x){
#if __has_builtin(__builtin_amdgcn_exp2f)
  return __builtin_amdgcn_exp2f(x);
#else
  return exp2f(x);
#endif
}

// ---- fp32 W[K][N] -> bf16 Wt[N][K] (LDS-tiled transpose+convert) ----
__global__ __launch_bounds__(256) void k_transpose_w(const float* __restrict__ W,
                                                     u16* __restrict__ Wt, int K, int N){
  __shared__ float tile[32][33];
  int n0 = blockIdx.x * 32, k0 = blockIdx.y * 32;
  int tx = threadIdx.x, ty = threadIdx.y;  // (32,8)
  #pragma unroll
  for (int r = 0; r < 4; ++r)
    tile[ty + r*8][tx] = W[(size_t)(k0 + ty + r*8) * N + n0 + tx];
  __syncthreads();
  #pragma unroll
  for (int r = 0; r < 4; ++r)
    Wt[(size_t)(n0 + ty + r*8) * K + k0 + tx] = f2bf(tile[tx][ty + r*8]);
}

// ---- per-head V transpose: Vt[(bh*128+d)*S + s] = V[(b*S+s)*D + h*128+d] ----
__global__ __launch_bounds__(256) void k_transpose_v(const u16* __restrict__ V,
                                                     u16* __restrict__ Vt){
  __shared__ u16 tile[32][33];
  int s0 = blockIdx.x * 32;
  int bh = blockIdx.y >> 2, dt = blockIdx.y & 3;
  int b = bh >> 4, h = bh & 15;
  int tx = threadIdx.x, ty = threadIdx.y;
  #pragma unroll
  for (int r = 0; r < 4; ++r)
    tile[ty + r*8][tx] = V[(size_t)(b*SS + s0 + ty + r*8) * D_MODEL + h*DK + dt*32 + tx];
  __syncthreads();
  #pragma unroll
  for (int r = 0; r < 4; ++r)
    Vt[(size_t)(bh*DK + dt*32 + ty + r*8) * SS + s0 + tx] = tile[tx][ty + r*8];
}

// ---- RMSNorm: fp32 row -> bf16 row (row = 2048) ----
__global__ __launch_bounds__(256) void k_rmsnorm(const float* __restrict__ X,
                                                 const float* __restrict__ g,
                                                 u16* __restrict__ out){
  int row = blockIdx.x, tid = threadIdx.x;
  const float* x = X + (size_t)row * D_MODEL;
  float4 a = ((const float4*)x)[tid*2];
  float4 b = ((const float4*)x)[tid*2+1];
  float ss = a.x*a.x + a.y*a.y + a.z*a.z + a.w*a.w
           + b.x*b.x + b.y*b.y + b.z*b.z + b.w*b.w;
  #pragma unroll
  for (int m = 1; m < 64; m <<= 1) ss += __shfl_xor(ss, m, 64);
  __shared__ float red[4];
  if ((tid & 63) == 0) red[tid >> 6] = ss;
  __syncthreads();
  float tot = red[0] + red[1] + red[2] + red[3];
  float sc = rsqrtf(tot * (1.0f / D_MODEL) + 1e-6f);
  float4 ga = ((const float4*)g)[tid*2];
  float4 gb = ((const float4*)g)[tid*2+1];
  uint32_t w0 = f2bf(a.x*sc*ga.x) | ((uint32_t)f2bf(a.y*sc*ga.y) << 16);
  uint32_t w1 = f2bf(a.z*sc*ga.z) | ((uint32_t)f2bf(a.w*sc*ga.w) << 16);
  uint32_t w2 = f2bf(b.x*sc*gb.x) | ((uint32_t)f2bf(b.y*sc*gb.y) << 16);
  uint32_t w3 = f2bf(b.z*sc*gb.z) | ((uint32_t)f2bf(b.w*sc*gb.w) << 16);
  ((uint4*)(out + (size_t)row * D_MODEL))[tid] = make_uint4(w0, w1, w2, w3);
}

// ---- bf16 GEMM, m97 structure: C[M][N] = A[M][K] * Bt[N][K]^T (+epilogue) ----
// EPI 0: bf16 out, +bias       (QKV)
// EPI 1: f32 out, +bias +res   (O proj)
// EPI 2: bf16 out, plain       (W1)
// EPI 3: f32 out, +res         (W2, final)
// EPI 4: bf16 out, silu(aux)*acc, in-place on aux (W3 fused with silu-mul)
template<int EPI>
__global__ __launch_bounds__(256) void k_gemm_bt(
    const u16* __restrict__ A, const u16* __restrict__ Bt,
    const float* __restrict__ bias, const float* __restrict__ res,
    const u16* __restrict__ aux,
    void* __restrict__ Cout, int M, int N, int K)
{
  __shared__ __align__(16) u16 As[128*32];
  __shared__ __align__(16) u16 Bs[128*32];
  int tid = threadIdx.x;
  int m0 = blockIdx.y * 128, n0 = blockIdx.x * 128;
  int lane = tid & 63, wave = tid >> 6;
  int wr = wave >> 1, wc = wave & 1;
  int lrow = lane & 15, lhi = lane >> 4;
  f32x4 acc[4][4] = {};
  int srow = tid >> 2;
  int scol = (tid & 3) * 8;
  const int nk = K >> 5;
  for (int kt = 0; kt < nk; ++kt){
    int k0 = kt << 5;
    #pragma unroll
    for (int c = 0; c < 2; ++c){
      int r = c*64 + srow;
      __builtin_amdgcn_global_load_lds(
        (const __attribute__((address_space(1))) void*)(A + (size_t)(m0 + r)*K + k0 + scol),
        (__attribute__((address_space(3))) void*)(&As[r*32 + scol]), 16, 0, 0);
      __builtin_amdgcn_global_load_lds(
        (const __attribute__((address_space(1))) void*)(Bt + (size_t)(n0 + r)*K + k0 + scol),
        (__attribute__((address_space(3))) void*)(&Bs[r*32 + scol]), 16, 0, 0);
    }
    __syncthreads();
    bf16x8 af[4], bfv[4];
    #pragma unroll
    for (int i = 0; i < 4; ++i){
      af[i]  = *(const bf16x8*)(&As[(wr*64 + i*16 + lrow)*32 + lhi*8]);
      bfv[i] = *(const bf16x8*)(&Bs[(wc*64 + i*16 + lrow)*32 + lhi*8]);
    }
    #pragma unroll
    for (int i = 0; i < 4; ++i)
      #pragma unroll
      for (int j = 0; j < 4; ++j)
        acc[i][j] = __builtin_amdgcn_mfma_f32_16x16x32_bf16(af[i], bfv[j], acc[i][j], 0, 0, 0);
    __syncthreads();
  }
  #pragma unroll
  for (int i = 0; i < 4; ++i){
    #pragma unroll
    for (int j = 0; j < 4; ++j){
      int col = n0 + wc*64 + j*16 + lrow;
      float bv = 0.f;
      if constexpr (EPI == 0 || EPI == 1) bv = bias[col];
      #pragma unroll
      for (int q = 0; q < 4; ++q){
        int row = m0 + wr*64 + i*16 + lhi*4 + q;
        size_t idx = (size_t)row*N + col;
        float v = acc[i][j][q] + bv;
        if constexpr (EPI == 1 || EPI == 3) v += res[idx];
        if constexpr (EPI == 4){
          float a0 = bf2f(aux[idx]);
          v = a0 / (1.f + __expf(-a0)) * v;
        }
        if constexpr (EPI == 0 || EPI == 2 || EPI == 4) ((u16*)Cout)[idx] = f2bf(v);
        else ((float*)Cout)[idx] = v;
      }
    }
  }
}

// ---- causal flash attention: 64 q-rows/block, 4 independent waves x 16 rows,
//      KVBLK=64, no block barriers, V reg-prefetch, swizzled per-wave P_lds ----
__global__ __launch_bounds__(256) void k_attn(
    const u16* __restrict__ Q, const u16* __restrict__ Kb,
    const u16* __restrict__ Vt, u16* __restrict__ O)
{
  int tid = threadIdx.x, lane = tid & 63, wave = tid >> 6;
  int lrow = lane & 15, lhi = lane >> 4;
  int bh = blockIdx.y, b = bh >> 4, h = bh & 15;
  int qs = blockIdx.x * 64;
  int qrow = qs + wave * 16;
  __shared__ __align__(16) u16 P_lds[4][16*64];  // per-wave [16 q][64 kv], XOR-swizzled
  char* pw = (char*)&P_lds[wave][0];
  const float sc2 = 0.08838834764831845f * 1.44269504088896340736f;  // /sqrt(128) * log2(e)

  bf16x8 qf[4];
  const u16* qbase = Q + (size_t)(b*SS + qrow + lrow)*D_MODEL + h*DK + lhi*8;
  #pragma unroll
  for (int dc = 0; dc < 4; ++dc) qf[dc] = *(const bf16x8*)(qbase + dc*32);

  f32x4 accO[8] = {};
  float mr[4] = {-1e30f,-1e30f,-1e30f,-1e30f};
  float lr[4] = {0.f,0.f,0.f,0.f};

  int ntiles = blockIdx.x + 1;
  for (int kt = 0; kt < ntiles; ++kt){
    int kv0 = kt << 6;
    // ---- QK^T: 4 halves x 4 dc = 16 MFMA ----
    f32x4 sf[4];
    #pragma unroll
    for (int hf = 0; hf < 4; ++hf){
      const u16* kb = Kb + (size_t)(b*SS + kv0 + hf*16 + lrow)*D_MODEL + h*DK + lhi*8;
      f32x4 a = {};
      #pragma unroll
      for (int dc = 0; dc < 4; ++dc)
        a = __builtin_amdgcn_mfma_f32_16x16x32_bf16(qf[dc], *(const bf16x8*)(kb + dc*32), a, 0, 0, 0);
      sf[hf] = a;
    }
    // ---- V prefetch into regs (hides under softmax) ----
    bf16x8 vf[8][2];
    const u16* vb = Vt + ((size_t)bh*DK + lrow)*SS + kv0 + lhi*8;
    #pragma unroll
    for (int f = 0; f < 8; ++f){
      vf[f][0] = *(const bf16x8*)(vb + (size_t)(f*16)*SS);
      vf[f][1] = *(const bf16x8*)(vb + (size_t)(f*16)*SS + 32);
    }
    // ---- online softmax, log2 domain ----
    float p[4][4], mx[4];
    #pragma unroll
    for (int q = 0; q < 4; ++q){
      int qg = qrow + lhi*4 + q;
      float s0 = sf[0][q]*sc2, s1 = sf[1][q]*sc2, s2 = sf[2][q]*sc2, s3 = sf[3][q]*sc2;
      if (kv0      + lrow > qg) s0 = -1e30f;
      if (kv0 + 16 + lrow > qg) s1 = -1e30f;
      if (kv0 + 32 + lrow > qg) s2 = -1e30f;
      if (kv0 + 48 + lrow > qg) s3 = -1e30f;
      p[q][0]=s0; p[q][1]=s1; p[q][2]=s2; p[q][3]=s3;
      float m = fmaxf(fmaxf(s0,s1), fmaxf(s2,s3));
      m = fmaxf(m, __shfl_xor(m, 1, 64));
      m = fmaxf(m, __shfl_xor(m, 2, 64));
      m = fmaxf(m, __shfl_xor(m, 4, 64));
      m = fmaxf(m, __shfl_xor(m, 8, 64));
      mx[q] = m;
    }
    float dmax = fmaxf(fmaxf(mx[0]-mr[0], mx[1]-mr[1]), fmaxf(mx[2]-mr[2], mx[3]-mr[3]));
    bool rescale = !__all(dmax <= 8.0f);   // T13 defer-max (2^8 headroom in fp32 accum)
    float al[4];
    #pragma unroll
    for (int q = 0; q < 4; ++q){
      if (rescale){
        float mn = fmaxf(mr[q], mx[q]);
        al[q] = fexp2(mr[q] - mn);
        mr[q] = mn;
      } else al[q] = 1.0f;
      p[q][0] = fexp2(p[q][0] - mr[q]);
      p[q][1] = fexp2(p[q][1] - mr[q]);
      p[q][2] = fexp2(p[q][2] - mr[q]);
      p[q][3] = fexp2(p[q][3] - mr[q]);
      float sm = (p[q][0] + p[q][1]) + (p[q][2] + p[q][3]);
      sm += __shfl_xor(sm, 1, 64);
      sm += __shfl_xor(sm, 2, 64);
      sm += __shfl_xor(sm, 4, 64);
      sm += __shfl_xor(sm, 8, 64);
      lr[q] = lr[q]*al[q] + sm;
    }
    if (rescale){
      #pragma unroll
      for (int f = 0; f < 8; ++f)
        #pragma unroll
        for (int q = 0; q < 4; ++q) accO[f][q] *= al[q];
    }
    // ---- P (D-layout) -> swizzled LDS -> A-layout ----
    #pragma unroll
    for (int q = 0; q < 4; ++q){
      int row = lhi*4 + q;
      int rb = row*128, sw = (row & 7) << 4;
      #pragma unroll
      for (int hf = 0; hf < 4; ++hf)
        *(u16*)(pw + rb + ((hf*32 + lrow*2) ^ sw)) = cvt_bf16(p[q][hf]);
    }
    __builtin_amdgcn_sched_barrier(0);  // keep ds_reads after ds_writes
    int rsw = (lrow & 7) << 4;
    bf16x8 pa0 = *(const bf16x8*)(pw + lrow*128 + ((      lhi*16) ^ rsw));
    bf16x8 pa1 = *(const bf16x8*)(pw + lrow*128 + ((64 + lhi*16) ^ rsw));
    #pragma unroll
    for (int f = 0; f < 8; ++f){
      accO[f] = __builtin_amdgcn_mfma_f32_16x16x32_bf16(pa0, vf[f][0], accO[f], 0, 0, 0);
      accO[f] = __builtin_amdgcn_mfma_f32_16x16x32_bf16(pa1, vf[f][1], accO[f], 0, 0, 0);
    }
  }
  #pragma unroll
  for (int q = 0; q < 4; ++q){
    float inv = 1.0f / lr[q];
    #pragma unroll
    for (int f = 0; f < 8; ++f){
      int row = b*SS + qrow + lhi*4 + q;
      int col = h*DK + f*16 + lrow;
      O[(size_t)row*D_MODEL + col] = cvt_bf16(accO[f][q] * inv);
    }
  }
}

extern "C" void kernel_launch(void* const* d_in, const int* in_sizes, int n_in,
                              void* d_out, int out_size, void* d_ws, size_t ws_size,
                              hipStream_t stream)
{
  (void)in_sizes; (void)n_in; (void)out_size;
  const float* x  = (const float*)d_in[0];
  const float* wq = (const float*)d_in[2];
  const float* bq = (const float*)d_in[3];
  const float* wk = (const float*)d_in[4];
  const float* bk = (const float*)d_in[5];
  const float* wv = (const float*)d_in[6];
  const float* bv = (const float*)d_in[7];
  const float* wo = (const float*)d_in[8];
  const float* bo = (const float*)d_in[9];
  const float* g1 = (const float*)d_in[10];
  const float* g2 = (const float*)d_in[11];
  const float* w1 = (const float*)d_in[12];
  const float* w3 = (const float*)d_in[13];  // w3 precedes w2 in dict order
  const float* w2 = (const float*)d_in[14];
  float* out = (float*)d_out;

  // ---- workspace layout (byte offsets), lifetime-aliased ----
  const size_t MB = 1u << 20;
  const size_t WFF = (size_t)D_MODEL * DFF * sizeof(u16);
  const size_t NEED = 112*MB + 3*WFF;
  if (ws_size < NEED) return;
  char* ws = (char*)d_ws;
  u16* bufA = (u16*)(ws + 0);        // 16 MiB: nbf1 -> aob -> nbf2
  u16* qbf  = (u16*)(ws + 16*MB);
  u16* kbf  = (u16*)(ws + 32*MB);
  u16* vbf  = (u16*)(ws + 48*MB);
  u16* h1   = qbf;                   // aliases qbf+kbf+vbf after attn
  u16* wqt  = (u16*)(ws + 64*MB);
  u16* wkt  = (u16*)(ws + 72*MB);
  u16* wvt  = (u16*)(ws + 80*MB);
  u16* wot  = (u16*)(ws + 88*MB);
  u16* vtb  = (u16*)(ws + 96*MB);
  u16* w1t  = (u16*)(ws + 112*MB);
  u16* w3t  = (u16*)(ws + 112*MB + WFF);
  u16* w2t  = (u16*)(ws + 112*MB + 2*WFF);
  // fp32 residual x1 lives in d_out

  dim3 tb(32, 8);
  k_transpose_w<<<dim3(64,64), tb, 0, stream>>>(wq, wqt, D_MODEL, D_MODEL);
  k_transpose_w<<<dim3(64,64), tb, 0, stream>>>(wk, wkt, D_MODEL, D_MODEL);
  k_transpose_w<<<dim3(64,64), tb, 0, stream>>>(wv, wvt, D_MODEL, D_MODEL);
  k_transpose_w<<<dim3(64,64), tb, 0, stream>>>(wo, wot, D_MODEL, D_MODEL);
  k_transpose_w<<<dim3(DFF/32,64), tb, 0, stream>>>(w1, w1t, D_MODEL, DFF);
  k_transpose_w<<<dim3(DFF/32,64), tb, 0, stream>>>(w3, w3t, D_MODEL, DFF);
  k_transpose_w<<<dim3(64,DFF/32), tb, 0, stream>>>(w2, w2t, DFF, D_MODEL);

  k_rmsnorm<<<MTOK, 256, 0, stream>>>(x, g1, bufA);
  k_gemm_bt<0><<<dim3(16,32), 256, 0, stream>>>(bufA, wqt, bq, nullptr, nullptr, qbf, MTOK, D_MODEL, D_MODEL);
  k_gemm_bt<0><<<dim3(16,32), 256, 0, stream>>>(bufA, wkt, bk, nullptr, nullptr, kbf, MTOK, D_MODEL, D_MODEL);
  k_gemm_bt<0><<<dim3(16,32), 256, 0, stream>>>(bufA, wvt, bv, nullptr, nullptr, vbf, MTOK, D_MODEL, D_MODEL);
  k_transpose_v<<<dim3(SS/32, 128), tb, 0, stream>>>(vbf, vtb);
  k_attn<<<dim3(SS/64, BB*NHEADS), 256, 0, stream>>>(qbf, kbf, vtb, bufA);
  k_gemm_bt<1><<<dim3(16,32), 256, 0, stream>>>(bufA, wot, bo, x, nullptr, out, MTOK, D_MODEL, D_MODEL);
  k_rmsnorm<<<MTOK, 256, 0, stream>>>(out, g2, bufA);
  k_gemm_bt<2><<<dim3(DFF/128,32), 256, 0, stream>>>(bufA, w1t, nullptr, nullptr, nullptr, h1, MTOK, DFF, D_MODEL);
  k_gemm_bt<4><<<dim3(DFF/128,32), 256, 0, stream>>>(bufA, w3t, nullptr, nullptr, h1, h1, MTOK, DFF, D_MODEL);
  k_gemm_bt<3><<<dim3(16,32), 256, 0, stream>>>(h1, w2t, nullptr, out, nullptr, out, MTOK, D_MODEL, DFF);
}

// Round 4
// 959.669 us; speedup vs baseline: 1.3833x; 1.3833x over previous
//
#include <hip/hip_runtime.h>
#include <stdint.h>

typedef unsigned short u16;
typedef __bf16 bf16x8 __attribute__((ext_vector_type(8)));
typedef float f32x4 __attribute__((ext_vector_type(4)));

#define D_MODEL 2048
#define NHEADS 16
#define DK 128
#define DFF 5504
#define BB 2
#define SS 2048
#define MTOK 4096  // B*S

#define AS1 __attribute__((address_space(1)))
#define AS3 __attribute__((address_space(3)))

__device__ __forceinline__ u16 f2bf(float f){
  union { float f; uint32_t u; } v; v.f = f;
  uint32_t r = v.u + 0x7fffu + ((v.u >> 16) & 1u);
  return (u16)(r >> 16);
}
__device__ __forceinline__ float bf2f(u16 u){
  union { uint32_t u; float f; } v; v.u = ((uint32_t)u) << 16;
  return v.f;
}
__device__ __forceinline__ u16 cvt_bf16(float f){
  union { __bf16 h; u16 u; } v; v.h = (__bf16)f; return v.u;
}
__device__ __forceinline__ float fexp2(float x){
#if __has_builtin(__builtin_amdgcn_exp2f)
  return __builtin_amdgcn_exp2f(x);
#else
  return exp2f(x);
#endif
}

// ---- fp32 W[K][N] -> bf16 Wt[N][K] (LDS-tiled transpose+convert) ----
__global__ __launch_bounds__(256) void k_transpose_w(const float* __restrict__ W,
                                                     u16* __restrict__ Wt, int K, int N){
  __shared__ float tile[32][33];
  int n0 = blockIdx.x * 32, k0 = blockIdx.y * 32;
  int tx = threadIdx.x, ty = threadIdx.y;  // (32,8)
  #pragma unroll
  for (int r = 0; r < 4; ++r)
    tile[ty + r*8][tx] = W[(size_t)(k0 + ty + r*8) * N + n0 + tx];
  __syncthreads();
  #pragma unroll
  for (int r = 0; r < 4; ++r)
    Wt[(size_t)(n0 + ty + r*8) * K + k0 + tx] = f2bf(tile[tx][ty + r*8]);
}

// ---- per-head V transpose: Vt[(bh*128+d)*S + s] = V[(b*S+s)*D + h*128+d] ----
__global__ __launch_bounds__(256) void k_transpose_v(const u16* __restrict__ V,
                                                     u16* __restrict__ Vt){
  __shared__ u16 tile[32][33];
  int s0 = blockIdx.x * 32;
  int bh = blockIdx.y >> 2, dt = blockIdx.y & 3;
  int b = bh >> 4, h = bh & 15;
  int tx = threadIdx.x, ty = threadIdx.y;
  #pragma unroll
  for (int r = 0; r < 4; ++r)
    tile[ty + r*8][tx] = V[(size_t)(b*SS + s0 + ty + r*8) * D_MODEL + h*DK + dt*32 + tx];
  __syncthreads();
  #pragma unroll
  for (int r = 0; r < 4; ++r)
    Vt[(size_t)(bh*DK + dt*32 + ty + r*8) * SS + s0 + tx] = tile[tx][ty + r*8];
}

// ---- RMSNorm: fp32 row -> bf16 row (row = 2048) ----
__global__ __launch_bounds__(256) void k_rmsnorm(const float* __restrict__ X,
                                                 const float* __restrict__ g,
                                                 u16* __restrict__ out){
  int row = blockIdx.x, tid = threadIdx.x;
  const float* x = X + (size_t)row * D_MODEL;
  float4 a = ((const float4*)x)[tid*2];
  float4 b = ((const float4*)x)[tid*2+1];
  float ss = a.x*a.x + a.y*a.y + a.z*a.z + a.w*a.w
           + b.x*b.x + b.y*b.y + b.z*b.z + b.w*b.w;
  #pragma unroll
  for (int m = 1; m < 64; m <<= 1) ss += __shfl_xor(ss, m, 64);
  __shared__ float red[4];
  if ((tid & 63) == 0) red[tid >> 6] = ss;
  __syncthreads();
  float tot = red[0] + red[1] + red[2] + red[3];
  float sc = rsqrtf(tot * (1.0f / D_MODEL) + 1e-6f);
  float4 ga = ((const float4*)g)[tid*2];
  float4 gb = ((const float4*)g)[tid*2+1];
  uint32_t w0 = f2bf(a.x*sc*ga.x) | ((uint32_t)f2bf(a.y*sc*ga.y) << 16);
  uint32_t w1 = f2bf(a.z*sc*ga.z) | ((uint32_t)f2bf(a.w*sc*ga.w) << 16);
  uint32_t w2 = f2bf(b.x*sc*gb.x) | ((uint32_t)f2bf(b.y*sc*gb.y) << 16);
  uint32_t w3 = f2bf(b.z*sc*gb.z) | ((uint32_t)f2bf(b.w*sc*gb.w) << 16);
  ((uint4*)(out + (size_t)row * D_MODEL))[tid] = make_uint4(w0, w1, w2, w3);
}

// ---- bf16 GEMM, m97 structure: C[M][N] = A[M][K] * Bt[N][K]^T (+epilogue) ----
// EPI 0: bf16 out, +bias       (QKV)
// EPI 1: f32 out, +bias +res   (O proj)
// EPI 2: bf16 out, plain       (W1)
// EPI 3: f32 out, +res         (W2, final)
// EPI 4: bf16 out, silu(aux)*acc, in-place on aux (W3 fused with silu-mul)
template<int EPI>
__global__ __launch_bounds__(256) void k_gemm_bt(
    const u16* __restrict__ A, const u16* __restrict__ Bt,
    const float* __restrict__ bias, const float* __restrict__ res,
    const u16* __restrict__ aux,
    void* __restrict__ Cout, int M, int N, int K)
{
  __shared__ __align__(16) u16 As[128*32];
  __shared__ __align__(16) u16 Bs[128*32];
  int tid = threadIdx.x;
  int m0 = blockIdx.y * 128, n0 = blockIdx.x * 128;
  int lane = tid & 63, wave = tid >> 6;
  int wr = wave >> 1, wc = wave & 1;
  int lrow = lane & 15, lhi = lane >> 4;
  f32x4 acc[4][4] = {};
  int srow = tid >> 2;
  int scol = (tid & 3) * 8;
  const int nk = K >> 5;
  for (int kt = 0; kt < nk; ++kt){
    int k0 = kt << 5;
    #pragma unroll
    for (int c = 0; c < 2; ++c){
      int r = c*64 + srow;
      __builtin_amdgcn_global_load_lds(
        (const AS1 void*)(A + (size_t)(m0 + r)*K + k0 + scol),
        (AS3 void*)(&As[r*32 + scol]), 16, 0, 0);
      __builtin_amdgcn_global_load_lds(
        (const AS1 void*)(Bt + (size_t)(n0 + r)*K + k0 + scol),
        (AS3 void*)(&Bs[r*32 + scol]), 16, 0, 0);
    }
    __syncthreads();
    bf16x8 af[4], bfv[4];
    #pragma unroll
    for (int i = 0; i < 4; ++i){
      af[i]  = *(const bf16x8*)(&As[(wr*64 + i*16 + lrow)*32 + lhi*8]);
      bfv[i] = *(const bf16x8*)(&Bs[(wc*64 + i*16 + lrow)*32 + lhi*8]);
    }
    #pragma unroll
    for (int i = 0; i < 4; ++i)
      #pragma unroll
      for (int j = 0; j < 4; ++j)
        acc[i][j] = __builtin_amdgcn_mfma_f32_16x16x32_bf16(af[i], bfv[j], acc[i][j], 0, 0, 0);
    __syncthreads();
  }
  #pragma unroll
  for (int i = 0; i < 4; ++i){
    #pragma unroll
    for (int j = 0; j < 4; ++j){
      int col = n0 + wc*64 + j*16 + lrow;
      float bv = 0.f;
      if constexpr (EPI == 0 || EPI == 1) bv = bias[col];
      #pragma unroll
      for (int q = 0; q < 4; ++q){
        int row = m0 + wr*64 + i*16 + lhi*4 + q;
        size_t idx = (size_t)row*N + col;
        float v = acc[i][j][q] + bv;
        if constexpr (EPI == 1 || EPI == 3) v += res[idx];
        if constexpr (EPI == 4){
          float a0 = bf2f(aux[idx]);
          v = a0 / (1.f + __expf(-a0)) * v;
        }
        if constexpr (EPI == 0 || EPI == 2 || EPI == 4) ((u16*)Cout)[idx] = f2bf(v);
        else ((float*)Cout)[idx] = v;
      }
    }
  }
}

// ---- causal flash attention, 2-phase pipelined LDS staging ----
// 64 q-rows/block (4 waves x 16), KVBLK=64. K and V^T tiles cooperatively
// staged via global_load_lds into double-buffered, XOR-swizzled LDS
// (pre-swizzled global source + swizzled ds_read: rule-21 both-sides).
// One __syncthreads per tile = the pipeline fence (vmcnt(0)+barrier).
__global__ __launch_bounds__(256) void k_attn(
    const u16* __restrict__ Q, const u16* __restrict__ Kb,
    const u16* __restrict__ Vt, u16* __restrict__ O)
{
  int tid = threadIdx.x, lane = tid & 63, wave = tid >> 6;
  int lrow = lane & 15, lhi = lane >> 4;
  int bh = blockIdx.y, b = bh >> 4, h = bh & 15;
  int qi = gridDim.x - 1 - blockIdx.x;   // longest blocks dispatched first
  int qs = qi * 64;
  int nt = qi + 1;
  int qrow = qs + wave * 16;

  __shared__ __align__(16) u16 Kbuf[2][64*128];   // 64 kv-rows x 256B
  __shared__ __align__(16) u16 Vbuf[2][128*64];   // 128 d-rows x 128B
  __shared__ __align__(16) u16 P_lds[4][16*64];   // per-wave P, swizzled
  char* pw = (char*)&P_lds[wave][0];
  const float sc2 = 0.08838834764831845f * 1.44269504088896340736f;  // /sqrt(128)*log2(e)

  // Q fragments (A-layout: row = lane&15, k = (lane>>4)*8+j)
  bf16x8 qf[4];
  const u16* qbase = Q + (size_t)(b*SS + qrow + lrow)*D_MODEL + h*DK + lhi*8;
  #pragma unroll
  for (int dc = 0; dc < 4; ++dc) qf[dc] = *(const bf16x8*)(qbase + dc*32);

  // cooperative stage of tile kt into buffer bufi (8 x global_load_lds / wave)
  auto stage = [&](int bufi, int kt){
    int kv0 = kt << 6;
    char* kd = (char*)&Kbuf[bufi][0];
    char* vd = (char*)&Vbuf[bufi][0];
    #pragma unroll
    for (int p = 0; p < 4; ++p){
      // K: row r (0..63), 16 chunks of 16B; LDS linear, src chunk = lane^r swizzle
      int r  = p*16 + wave*4 + (lane >> 4);
      int cg = (lane & 15) ^ (r & 7);
      __builtin_amdgcn_global_load_lds(
        (const AS1 void*)(Kb + (size_t)(b*SS + kv0 + r)*D_MODEL + h*DK + cg*8),
        (AS3 void*)(kd + p*4096 + wave*1024 + lane*16), 16, 0, 0);
      // V^T: row d (0..127), 8 chunks of 16B
      int d  = p*32 + wave*8 + (lane >> 3);
      int cv = (lane & 7) ^ (d & 7);
      __builtin_amdgcn_global_load_lds(
        (const AS1 void*)(Vt + (size_t)bh*DK*SS + (size_t)d*SS + kv0 + cv*8),
        (AS3 void*)(vd + p*4096 + wave*1024 + lane*16), 16, 0, 0);
    }
  };

  f32x4 accO[8] = {};
  float mr[4] = {-1e30f,-1e30f,-1e30f,-1e30f};
  float lr[4] = {0.f,0.f,0.f,0.f};

  stage(0, 0);
  __syncthreads();

  for (int kt = 0; kt < nt; ++kt){
    int cur = kt & 1;
    if (kt + 1 < nt) stage(cur ^ 1, kt + 1);
    int kv0 = kt << 6;
    const char* kl = (const char*)&Kbuf[cur][0];
    const char* vl = (const char*)&Vbuf[cur][0];

    // ---- QK^T: 16 MFMA, K-frags from swizzled LDS ----
    f32x4 sf[4];
    #pragma unroll
    for (int hf = 0; hf < 4; ++hf){
      int rl = hf*16 + lrow;
      int sw = rl & 7;
      f32x4 a = {};
      #pragma unroll
      for (int dc = 0; dc < 4; ++dc){
        bf16x8 kf = *(const bf16x8*)(kl + rl*256 + (((lhi + dc*4) ^ sw) << 4));
        a = __builtin_amdgcn_mfma_f32_16x16x32_bf16(qf[dc], kf, a, 0, 0, 0);
      }
      sf[hf] = a;
    }

    // ---- online softmax (log2 domain), mask only on diagonal tile ----
    float p[4][4], mx[4];
    #pragma unroll
    for (int q = 0; q < 4; ++q){
      float s0 = sf[0][q]*sc2, s1 = sf[1][q]*sc2, s2 = sf[2][q]*sc2, s3 = sf[3][q]*sc2;
      if (kt == nt - 1){
        int qg = qrow + lhi*4 + q;
        if (kv0      + lrow > qg) s0 = -1e30f;
        if (kv0 + 16 + lrow > qg) s1 = -1e30f;
        if (kv0 + 32 + lrow > qg) s2 = -1e30f;
        if (kv0 + 48 + lrow > qg) s3 = -1e30f;
      }
      p[q][0]=s0; p[q][1]=s1; p[q][2]=s2; p[q][3]=s3;
      float m = fmaxf(fmaxf(s0,s1), fmaxf(s2,s3));
      m = fmaxf(m, __shfl_xor(m, 1, 64));
      m = fmaxf(m, __shfl_xor(m, 2, 64));
      m = fmaxf(m, __shfl_xor(m, 4, 64));
      m = fmaxf(m, __shfl_xor(m, 8, 64));
      mx[q] = m;
    }
    float dmax = fmaxf(fmaxf(mx[0]-mr[0], mx[1]-mr[1]), fmaxf(mx[2]-mr[2], mx[3]-mr[3]));
    bool rescale = !__all(dmax <= 8.0f);   // T13 defer-max
    float al[4];
    #pragma unroll
    for (int q = 0; q < 4; ++q){
      if (rescale){
        float mn = fmaxf(mr[q], mx[q]);
        al[q] = fexp2(mr[q] - mn);
        mr[q] = mn;
      } else al[q] = 1.0f;
      p[q][0] = fexp2(p[q][0] - mr[q]);
      p[q][1] = fexp2(p[q][1] - mr[q]);
      p[q][2] = fexp2(p[q][2] - mr[q]);
      p[q][3] = fexp2(p[q][3] - mr[q]);
      float sm = (p[q][0] + p[q][1]) + (p[q][2] + p[q][3]);
      sm += __shfl_xor(sm, 1, 64);
      sm += __shfl_xor(sm, 2, 64);
      sm += __shfl_xor(sm, 4, 64);
      sm += __shfl_xor(sm, 8, 64);
      lr[q] = lr[q]*al[q] + sm;
    }
    if (rescale){
      #pragma unroll
      for (int f = 0; f < 8; ++f)
        #pragma unroll
        for (int q = 0; q < 4; ++q) accO[f][q] *= al[q];
    }

    // ---- P (D-layout) -> swizzled per-wave LDS -> A-layout ----
    #pragma unroll
    for (int q = 0; q < 4; ++q){
      int row = lhi*4 + q;
      int rb = row*128, sw = (row & 7) << 4;
      #pragma unroll
      for (int hf = 0; hf < 4; ++hf)
        *(u16*)(pw + rb + ((hf*32 + lrow*2) ^ sw)) = cvt_bf16(p[q][hf]);
    }
    __builtin_amdgcn_sched_barrier(0);  // keep P ds_reads after ds_writes
    int rsw = (lrow & 7) << 4;
    bf16x8 pa0 = *(const bf16x8*)(pw + lrow*128 + ((     lhi*16) ^ rsw));
    bf16x8 pa1 = *(const bf16x8*)(pw + lrow*128 + ((64 + lhi*16) ^ rsw));

    // ---- PV: 16 MFMA, V^T frags from swizzled LDS ----
    #pragma unroll
    for (int f = 0; f < 8; ++f){
      int d = f*16 + lrow;
      int swv = d & 7;
      bf16x8 v0 = *(const bf16x8*)(vl + d*128 + (((lhi    ) ^ swv) << 4));
      bf16x8 v1 = *(const bf16x8*)(vl + d*128 + (((lhi + 4) ^ swv) << 4));
      accO[f] = __builtin_amdgcn_mfma_f32_16x16x32_bf16(pa0, v0, accO[f], 0, 0, 0);
      accO[f] = __builtin_amdgcn_mfma_f32_16x16x32_bf16(pa1, v1, accO[f], 0, 0, 0);
    }

    __syncthreads();  // vmcnt(0)+lgkmcnt(0)+barrier: next tile staged, bufs free
  }

  #pragma unroll
  for (int q = 0; q < 4; ++q){
    float inv = 1.0f / lr[q];
    #pragma unroll
    for (int f = 0; f < 8; ++f){
      int row = b*SS + qrow + lhi*4 + q;
      int col = h*DK + f*16 + lrow;
      O[(size_t)row*D_MODEL + col] = cvt_bf16(accO[f][q] * inv);
    }
  }
}

extern "C" void kernel_launch(void* const* d_in, const int* in_sizes, int n_in,
                              void* d_out, int out_size, void* d_ws, size_t ws_size,
                              hipStream_t stream)
{
  (void)in_sizes; (void)n_in; (void)out_size;
  const float* x  = (const float*)d_in[0];
  const float* wq = (const float*)d_in[2];
  const float* bq = (const float*)d_in[3];
  const float* wk = (const float*)d_in[4];
  const float* bk = (const float*)d_in[5];
  const float* wv = (const float*)d_in[6];
  const float* bv = (const float*)d_in[7];
  const float* wo = (const float*)d_in[8];
  const float* bo = (const float*)d_in[9];
  const float* g1 = (const float*)d_in[10];
  const float* g2 = (const float*)d_in[11];
  const float* w1 = (const float*)d_in[12];
  const float* w3 = (const float*)d_in[13];  // w3 precedes w2 in dict order
  const float* w2 = (const float*)d_in[14];
  float* out = (float*)d_out;

  // ---- workspace layout (byte offsets), lifetime-aliased ----
  const size_t MB = 1u << 20;
  const size_t WFF = (size_t)D_MODEL * DFF * sizeof(u16);
  const size_t NEED = 112*MB + 3*WFF;
  if (ws_size < NEED) return;
  char* ws = (char*)d_ws;
  u16* bufA = (u16*)(ws + 0);        // 16 MiB: nbf1 -> aob -> nbf2
  u16* qbf  = (u16*)(ws + 16*MB);
  u16* kbf  = (u16*)(ws + 32*MB);
  u16* vbf  = (u16*)(ws + 48*MB);
  u16* h1   = qbf;                   // aliases qbf+kbf+vbf after attn
  u16* wqt  = (u16*)(ws + 64*MB);
  u16* wkt  = (u16*)(ws + 72*MB);
  u16* wvt  = (u16*)(ws + 80*MB);
  u16* wot  = (u16*)(ws + 88*MB);
  u16* vtb  = (u16*)(ws + 96*MB);
  u16* w1t  = (u16*)(ws + 112*MB);
  u16* w3t  = (u16*)(ws + 112*MB + WFF);
  u16* w2t  = (u16*)(ws + 112*MB + 2*WFF);
  // fp32 residual x1 lives in d_out

  dim3 tb(32, 8);
  k_transpose_w<<<dim3(64,64), tb, 0, stream>>>(wq, wqt, D_MODEL, D_MODEL);
  k_transpose_w<<<dim3(64,64), tb, 0, stream>>>(wk, wkt, D_MODEL, D_MODEL);
  k_transpose_w<<<dim3(64,64), tb, 0, stream>>>(wv, wvt, D_MODEL, D_MODEL);
  k_transpose_w<<<dim3(64,64), tb, 0, stream>>>(wo, wot, D_MODEL, D_MODEL);
  k_transpose_w<<<dim3(DFF/32,64), tb, 0, stream>>>(w1, w1t, D_MODEL, DFF);
  k_transpose_w<<<dim3(DFF/32,64), tb, 0, stream>>>(w3, w3t, D_MODEL, DFF);
  k_transpose_w<<<dim3(64,DFF/32), tb, 0, stream>>>(w2, w2t, DFF, D_MODEL);

  k_rmsnorm<<<MTOK, 256, 0, stream>>>(x, g1, bufA);
  k_gemm_bt<0><<<dim3(16,32), 256, 0, stream>>>(bufA, wqt, bq, nullptr, nullptr, qbf, MTOK, D_MODEL, D_MODEL);
  k_gemm_bt<0><<<dim3(16,32), 256, 0, stream>>>(bufA, wkt, bk, nullptr, nullptr, kbf, MTOK, D_MODEL, D_MODEL);
  k_gemm_bt<0><<<dim3(16,32), 256, 0, stream>>>(bufA, wvt, bv, nullptr, nullptr, vbf, MTOK, D_MODEL, D_MODEL);
  k_transpose_v<<<dim3(SS/32, 128), tb, 0, stream>>>(vbf, vtb);
  k_attn<<<dim3(SS/64, BB*NHEADS), 256, 0, stream>>>(qbf, kbf, vtb, bufA);
  k_gemm_bt<1><<<dim3(16,32), 256, 0, stream>>>(bufA, wot, bo, x, nullptr, out, MTOK, D_MODEL, D_MODEL);
  k_rmsnorm<<<MTOK, 256, 0, stream>>>(out, g2, bufA);
  k_gemm_bt<2><<<dim3(DFF/128,32), 256, 0, stream>>>(bufA, w1t, nullptr, nullptr, nullptr, h1, MTOK, DFF, D_MODEL);
  k_gemm_bt<4><<<dim3(DFF/128,32), 256, 0, stream>>>(bufA, w3t, nullptr, nullptr, h1, h1, MTOK, DFF, D_MODEL);
  k_gemm_bt<3><<<dim3(16,32), 256, 0, stream>>>(h1, w2t, nullptr, out, nullptr, out, MTOK, D_MODEL, DFF);
}

// Round 5
// 858.083 us; speedup vs baseline: 1.5470x; 1.1184x over previous
//
#include <hip/hip_runtime.h>
#include <stdint.h>

typedef unsigned short u16;
typedef __bf16 bf16x8 __attribute__((ext_vector_type(8)));
typedef float f32x4 __attribute__((ext_vector_type(4)));

#define D_MODEL 2048
#define NHEADS 16
#define DK 128
#define DFF 5504
#define BB 2
#define SS 2048
#define MTOK 4096  // B*S
#define DQKV 6144  // fused QKV width

#define AS1 __attribute__((address_space(1)))
#define AS3 __attribute__((address_space(3)))

__device__ __forceinline__ u16 f2bf(float f){
  union { float f; uint32_t u; } v; v.f = f;
  uint32_t r = v.u + 0x7fffu + ((v.u >> 16) & 1u);
  return (u16)(r >> 16);
}
__device__ __forceinline__ float bf2f(u16 u){
  union { uint32_t u; float f; } v; v.u = ((uint32_t)u) << 16;
  return v.f;
}
__device__ __forceinline__ u16 cvt_bf16(float f){
  union { __bf16 h; u16 u; } v; v.h = (__bf16)f; return v.u;
}
__device__ __forceinline__ float fexp2(float x){
#if __has_builtin(__builtin_amdgcn_exp2f)
  return __builtin_amdgcn_exp2f(x);
#else
  return exp2f(x);
#endif
}

// ---- fp32 W[K][N] -> bf16 Wt[N][K] (LDS-tiled transpose+convert) ----
__global__ __launch_bounds__(256) void k_transpose_w(const float* __restrict__ W,
                                                     u16* __restrict__ Wt, int K, int N){
  __shared__ float tile[32][33];
  int n0 = blockIdx.x * 32, k0 = blockIdx.y * 32;
  int tx = threadIdx.x, ty = threadIdx.y;  // (32,8)
  #pragma unroll
  for (int r = 0; r < 4; ++r)
    tile[ty + r*8][tx] = W[(size_t)(k0 + ty + r*8) * N + n0 + tx];
  __syncthreads();
  #pragma unroll
  for (int r = 0; r < 4; ++r)
    Wt[(size_t)(n0 + ty + r*8) * K + k0 + tx] = f2bf(tile[tx][ty + r*8]);
}

// ---- per-head V transpose from fused QKV: Vt[(bh*128+d)*S + s] = V[(b*S+s)*ld + d'] ----
__global__ __launch_bounds__(256) void k_transpose_v(const u16* __restrict__ V,
                                                     u16* __restrict__ Vt, int ld){
  __shared__ u16 tile[32][33];
  int s0 = blockIdx.x * 32;
  int bh = blockIdx.y >> 2, dt = blockIdx.y & 3;
  int b = bh >> 4, h = bh & 15;
  int tx = threadIdx.x, ty = threadIdx.y;
  #pragma unroll
  for (int r = 0; r < 4; ++r)
    tile[ty + r*8][tx] = V[(size_t)(b*SS + s0 + ty + r*8) * ld + h*DK + dt*32 + tx];
  __syncthreads();
  #pragma unroll
  for (int r = 0; r < 4; ++r)
    Vt[(size_t)(bh*DK + dt*32 + ty + r*8) * SS + s0 + tx] = tile[tx][ty + r*8];
}

// ---- concat 3 bias vectors (2048 each) into one 6144 ----
__global__ __launch_bounds__(256) void k_concat3(const float* __restrict__ a,
                                                 const float* __restrict__ b,
                                                 const float* __restrict__ c,
                                                 float* __restrict__ o){
  int i = blockIdx.x*256 + threadIdx.x;
  if (i >= DQKV) return;
  o[i] = (i < 2048) ? a[i] : (i < 4096 ? b[i-2048] : c[i-4096]);
}

// ---- RMSNorm: fp32 row -> bf16 row (row = 2048) ----
__global__ __launch_bounds__(256) void k_rmsnorm(const float* __restrict__ X,
                                                 const float* __restrict__ g,
                                                 u16* __restrict__ out){
  int row = blockIdx.x, tid = threadIdx.x;
  const float* x = X + (size_t)row * D_MODEL;
  float4 a = ((const float4*)x)[tid*2];
  float4 b = ((const float4*)x)[tid*2+1];
  float ss = a.x*a.x + a.y*a.y + a.z*a.z + a.w*a.w
           + b.x*b.x + b.y*b.y + b.z*b.z + b.w*b.w;
  #pragma unroll
  for (int m = 1; m < 64; m <<= 1) ss += __shfl_xor(ss, m, 64);
  __shared__ float red[4];
  if ((tid & 63) == 0) red[tid >> 6] = ss;
  __syncthreads();
  float tot = red[0] + red[1] + red[2] + red[3];
  float sc = rsqrtf(tot * (1.0f / D_MODEL) + 1e-6f);
  float4 ga = ((const float4*)g)[tid*2];
  float4 gb = ((const float4*)g)[tid*2+1];
  uint32_t w0 = f2bf(a.x*sc*ga.x) | ((uint32_t)f2bf(a.y*sc*ga.y) << 16);
  uint32_t w1 = f2bf(a.z*sc*ga.z) | ((uint32_t)f2bf(a.w*sc*ga.w) << 16);
  uint32_t w2 = f2bf(b.x*sc*gb.x) | ((uint32_t)f2bf(b.y*sc*gb.y) << 16);
  uint32_t w3 = f2bf(b.z*sc*gb.z) | ((uint32_t)f2bf(b.w*sc*gb.w) << 16);
  ((uint4*)(out + (size_t)row * D_MODEL))[tid] = make_uint4(w0, w1, w2, w3);
}

// ---- bf16 GEMM: C[M][N] = A[M][K] * Bt[N][K]^T (+epilogue) ----
// Triple-buffered LDS, counted vmcnt (T3/T4), bijective XCD swizzle (T1).
// 1D grid: nwg = (M/128)*(N/128), row-major over N after swizzle.
// EPI 0: bf16 out, +bias       (QKV fused)
// EPI 1: f32 out, +bias +res   (O proj)
// EPI 2: bf16 out, plain       (W1)
// EPI 3: f32 out, +res         (W2, final)
// EPI 4: bf16 out, silu(aux)*acc, in-place on aux (W3 fused with silu-mul)
template<int EPI>
__global__ __launch_bounds__(256) void k_gemm_bt(
    const u16* __restrict__ A, const u16* __restrict__ Bt,
    const float* __restrict__ bias, const float* __restrict__ res,
    const u16* __restrict__ aux,
    void* __restrict__ Cout, int M, int N, int K)
{
  __shared__ __align__(16) u16 As[3][128*32];
  __shared__ __align__(16) u16 Bs[3][128*32];
  int tid = threadIdx.x;

  // T1: bijective XCD swizzle (m204), then row-major over N (A-panel reuse per XCD)
  int nwg = gridDim.x, wg = blockIdx.x;
  int qq = nwg >> 3, rr = nwg & 7;
  int xcd = wg & 7, sub = wg >> 3;
  int swz = (xcd < rr ? xcd*(qq+1) : rr*(qq+1) + (xcd-rr)*qq) + sub;
  int nbx = N >> 7;
  int m0 = (swz / nbx) << 7, n0 = (swz % nbx) << 7;

  int lane = tid & 63, wave = tid >> 6;
  int wr = wave >> 1, wc = wave & 1;
  int lrow = lane & 15, lhi = lane >> 4;
  f32x4 acc[4][4] = {};
  int srow = tid >> 2;
  int scol = (tid & 3) * 8;
  const int nk = K >> 5;

  auto stage = [&](int slot, int kt){
    int k0 = kt << 5;
    #pragma unroll
    for (int c = 0; c < 2; ++c){
      int r = c*64 + srow;
      __builtin_amdgcn_global_load_lds(
        (const AS1 void*)(A + (size_t)(m0 + r)*K + k0 + scol),
        (AS3 void*)(&As[slot][r*32 + scol]), 16, 0, 0);
      __builtin_amdgcn_global_load_lds(
        (const AS1 void*)(Bt + (size_t)(n0 + r)*K + k0 + scol),
        (AS3 void*)(&Bs[slot][r*32 + scol]), 16, 0, 0);
    }
  };

  stage(0, 0);
  if (nk > 1) stage(1, 1);
  if (nk > 1) asm volatile("s_waitcnt vmcnt(4)" ::: "memory");
  else        asm volatile("s_waitcnt vmcnt(0)" ::: "memory");
  __builtin_amdgcn_s_barrier();

  for (int kt = 0; kt < nk; ++kt){
    int cur = kt % 3;
    if (kt + 2 < nk) stage((kt + 2) % 3, kt + 2);
    bf16x8 af[4], bfv[4];
    #pragma unroll
    for (int i = 0; i < 4; ++i){
      af[i]  = *(const bf16x8*)(&As[cur][(wr*64 + i*16 + lrow)*32 + lhi*8]);
      bfv[i] = *(const bf16x8*)(&Bs[cur][(wc*64 + i*16 + lrow)*32 + lhi*8]);
    }
    #pragma unroll
    for (int i = 0; i < 4; ++i)
      #pragma unroll
      for (int j = 0; j < 4; ++j)
        acc[i][j] = __builtin_amdgcn_mfma_f32_16x16x32_bf16(af[i], bfv[j], acc[i][j], 0, 0, 0);
    // counted drain: keep newest tile's 8 loads in flight (T4: never 0 mid-loop)
    if (kt + 2 < nk) asm volatile("s_waitcnt vmcnt(4)" ::: "memory");
    else             asm volatile("s_waitcnt vmcnt(0)" ::: "memory");
    __builtin_amdgcn_s_barrier();
  }

  #pragma unroll
  for (int i = 0; i < 4; ++i){
    #pragma unroll
    for (int j = 0; j < 4; ++j){
      int col = n0 + wc*64 + j*16 + lrow;
      float bv = 0.f;
      if constexpr (EPI == 0 || EPI == 1) bv = bias[col];
      #pragma unroll
      for (int q = 0; q < 4; ++q){
        int row = m0 + wr*64 + i*16 + lhi*4 + q;
        size_t idx = (size_t)row*N + col;
        float v = acc[i][j][q] + bv;
        if constexpr (EPI == 1 || EPI == 3) v += res[idx];
        if constexpr (EPI == 4){
          float a0 = bf2f(aux[idx]);
          v = a0 / (1.f + __expf(-a0)) * v;
        }
        if constexpr (EPI == 0 || EPI == 2 || EPI == 4) ((u16*)Cout)[idx] = f2bf(v);
        else ((float*)Cout)[idx] = v;
      }
    }
  }
}

// ---- causal flash attention, 2-phase pipelined LDS staging ----
// Q/K read from fused QKV buffer with row stride ldq.
__global__ __launch_bounds__(256) void k_attn(
    const u16* __restrict__ Q, const u16* __restrict__ Kb,
    const u16* __restrict__ Vt, u16* __restrict__ O, int ldq)
{
  int tid = threadIdx.x, lane = tid & 63, wave = tid >> 6;
  int lrow = lane & 15, lhi = lane >> 4;
  int bh = blockIdx.y, b = bh >> 4, h = bh & 15;
  int qi = gridDim.x - 1 - blockIdx.x;   // longest blocks dispatched first
  int qs = qi * 64;
  int nt = qi + 1;
  int qrow = qs + wave * 16;

  __shared__ __align__(16) u16 Kbuf[2][64*128];
  __shared__ __align__(16) u16 Vbuf[2][128*64];
  __shared__ __align__(16) u16 P_lds[4][16*64];
  char* pw = (char*)&P_lds[wave][0];
  const float sc2 = 0.08838834764831845f * 1.44269504088896340736f;

  bf16x8 qf[4];
  const u16* qbase = Q + (size_t)(b*SS + qrow + lrow)*ldq + h*DK + lhi*8;
  #pragma unroll
  for (int dc = 0; dc < 4; ++dc) qf[dc] = *(const bf16x8*)(qbase + dc*32);

  auto stage = [&](int bufi, int kt){
    int kv0 = kt << 6;
    char* kd = (char*)&Kbuf[bufi][0];
    char* vd = (char*)&Vbuf[bufi][0];
    #pragma unroll
    for (int p = 0; p < 4; ++p){
      int r  = p*16 + wave*4 + (lane >> 4);
      int cg = (lane & 15) ^ (r & 7);
      __builtin_amdgcn_global_load_lds(
        (const AS1 void*)(Kb + (size_t)(b*SS + kv0 + r)*ldq + h*DK + cg*8),
        (AS3 void*)(kd + p*4096 + wave*1024 + lane*16), 16, 0, 0);
      int d  = p*32 + wave*8 + (lane >> 3);
      int cv = (lane & 7) ^ (d & 7);
      __builtin_amdgcn_global_load_lds(
        (const AS1 void*)(Vt + (size_t)bh*DK*SS + (size_t)d*SS + kv0 + cv*8),
        (AS3 void*)(vd + p*4096 + wave*1024 + lane*16), 16, 0, 0);
    }
  };

  f32x4 accO[8] = {};
  float mr[4] = {-1e30f,-1e30f,-1e30f,-1e30f};
  float lr[4] = {0.f,0.f,0.f,0.f};

  stage(0, 0);
  __syncthreads();

  for (int kt = 0; kt < nt; ++kt){
    int cur = kt & 1;
    if (kt + 1 < nt) stage(cur ^ 1, kt + 1);
    int kv0 = kt << 6;
    const char* kl = (const char*)&Kbuf[cur][0];
    const char* vl = (const char*)&Vbuf[cur][0];

    f32x4 sf[4];
    #pragma unroll
    for (int hf = 0; hf < 4; ++hf){
      int rl = hf*16 + lrow;
      int sw = rl & 7;
      f32x4 a = {};
      #pragma unroll
      for (int dc = 0; dc < 4; ++dc){
        bf16x8 kf = *(const bf16x8*)(kl + rl*256 + (((lhi + dc*4) ^ sw) << 4));
        a = __builtin_amdgcn_mfma_f32_16x16x32_bf16(qf[dc], kf, a, 0, 0, 0);
      }
      sf[hf] = a;
    }

    float p[4][4], mx[4];
    #pragma unroll
    for (int q = 0; q < 4; ++q){
      float s0 = sf[0][q]*sc2, s1 = sf[1][q]*sc2, s2 = sf[2][q]*sc2, s3 = sf[3][q]*sc2;
      if (kt == nt - 1){
        int qg = qrow + lhi*4 + q;
        if (kv0      + lrow > qg) s0 = -1e30f;
        if (kv0 + 16 + lrow > qg) s1 = -1e30f;
        if (kv0 + 32 + lrow > qg) s2 = -1e30f;
        if (kv0 + 48 + lrow > qg) s3 = -1e30f;
      }
      p[q][0]=s0; p[q][1]=s1; p[q][2]=s2; p[q][3]=s3;
      float m = fmaxf(fmaxf(s0,s1), fmaxf(s2,s3));
      m = fmaxf(m, __shfl_xor(m, 1, 64));
      m = fmaxf(m, __shfl_xor(m, 2, 64));
      m = fmaxf(m, __shfl_xor(m, 4, 64));
      m = fmaxf(m, __shfl_xor(m, 8, 64));
      mx[q] = m;
    }
    float dmax = fmaxf(fmaxf(mx[0]-mr[0], mx[1]-mr[1]), fmaxf(mx[2]-mr[2], mx[3]-mr[3]));
    bool rescale = !__all(dmax <= 8.0f);
    float al[4];
    #pragma unroll
    for (int q = 0; q < 4; ++q){
      if (rescale){
        float mn = fmaxf(mr[q], mx[q]);
        al[q] = fexp2(mr[q] - mn);
        mr[q] = mn;
      } else al[q] = 1.0f;
      p[q][0] = fexp2(p[q][0] - mr[q]);
      p[q][1] = fexp2(p[q][1] - mr[q]);
      p[q][2] = fexp2(p[q][2] - mr[q]);
      p[q][3] = fexp2(p[q][3] - mr[q]);
      float sm = (p[q][0] + p[q][1]) + (p[q][2] + p[q][3]);
      sm += __shfl_xor(sm, 1, 64);
      sm += __shfl_xor(sm, 2, 64);
      sm += __shfl_xor(sm, 4, 64);
      sm += __shfl_xor(sm, 8, 64);
      lr[q] = lr[q]*al[q] + sm;
    }
    if (rescale){
      #pragma unroll
      for (int f = 0; f < 8; ++f)
        #pragma unroll
        for (int q = 0; q < 4; ++q) accO[f][q] *= al[q];
    }

    #pragma unroll
    for (int q = 0; q < 4; ++q){
      int row = lhi*4 + q;
      int rb = row*128, sw = (row & 7) << 4;
      #pragma unroll
      for (int hf = 0; hf < 4; ++hf)
        *(u16*)(pw + rb + ((hf*32 + lrow*2) ^ sw)) = cvt_bf16(p[q][hf]);
    }
    __builtin_amdgcn_sched_barrier(0);
    int rsw = (lrow & 7) << 4;
    bf16x8 pa0 = *(const bf16x8*)(pw + lrow*128 + ((     lhi*16) ^ rsw));
    bf16x8 pa1 = *(const bf16x8*)(pw + lrow*128 + ((64 + lhi*16) ^ rsw));

    #pragma unroll
    for (int f = 0; f < 8; ++f){
      int d = f*16 + lrow;
      int swv = d & 7;
      bf16x8 v0 = *(const bf16x8*)(vl + d*128 + (((lhi    ) ^ swv) << 4));
      bf16x8 v1 = *(const bf16x8*)(vl + d*128 + (((lhi + 4) ^ swv) << 4));
      accO[f] = __builtin_amdgcn_mfma_f32_16x16x32_bf16(pa0, v0, accO[f], 0, 0, 0);
      accO[f] = __builtin_amdgcn_mfma_f32_16x16x32_bf16(pa1, v1, accO[f], 0, 0, 0);
    }

    __syncthreads();
  }

  #pragma unroll
  for (int q = 0; q < 4; ++q){
    float inv = 1.0f / lr[q];
    #pragma unroll
    for (int f = 0; f < 8; ++f){
      int row = b*SS + qrow + lhi*4 + q;
      int col = h*DK + f*16 + lrow;
      O[(size_t)row*D_MODEL + col] = cvt_bf16(accO[f][q] * inv);
    }
  }
}

extern "C" void kernel_launch(void* const* d_in, const int* in_sizes, int n_in,
                              void* d_out, int out_size, void* d_ws, size_t ws_size,
                              hipStream_t stream)
{
  (void)in_sizes; (void)n_in; (void)out_size;
  const float* x  = (const float*)d_in[0];
  const float* wq = (const float*)d_in[2];
  const float* bq = (const float*)d_in[3];
  const float* wk = (const float*)d_in[4];
  const float* bk = (const float*)d_in[5];
  const float* wv = (const float*)d_in[6];
  const float* bv = (const float*)d_in[7];
  const float* wo = (const float*)d_in[8];
  const float* bo = (const float*)d_in[9];
  const float* g1 = (const float*)d_in[10];
  const float* g2 = (const float*)d_in[11];
  const float* w1 = (const float*)d_in[12];
  const float* w3 = (const float*)d_in[13];  // w3 precedes w2 in dict order
  const float* w2 = (const float*)d_in[14];
  float* out = (float*)d_out;

  // ---- workspace layout (byte offsets), lifetime-aliased ----
  const size_t MB = 1u << 20;
  const size_t WFF = (size_t)D_MODEL * DFF * sizeof(u16);
  const size_t NEED = 112*MB + 3*WFF + 32768;
  if (ws_size < NEED) return;
  char* ws = (char*)d_ws;
  u16* bufA = (u16*)(ws + 0);        // 16 MiB: nbf1 -> aob -> nbf2
  u16* qkv  = (u16*)(ws + 16*MB);    // 48 MiB fused QKV [4096][6144]
  u16* h1   = qkv;                   // 45.1 MiB, aliases qkv after attn
  u16* wqkvt= (u16*)(ws + 64*MB);    // 24 MiB: wq^T|wk^T|wv^T contiguous [6144][2048]
  u16* wot  = (u16*)(ws + 88*MB);
  u16* vtb  = (u16*)(ws + 96*MB);    // 16 MiB
  u16* w1t  = (u16*)(ws + 112*MB);
  u16* w3t  = (u16*)(ws + 112*MB + WFF);
  u16* w2t  = (u16*)(ws + 112*MB + 2*WFF);
  float* bqkv = (float*)(ws + 112*MB + 3*WFF);  // 24 KiB concat bias
  // fp32 residual x1 lives in d_out

  dim3 tb(32, 8);
  k_transpose_w<<<dim3(64,64), tb, 0, stream>>>(wq, wqkvt,              D_MODEL, D_MODEL);
  k_transpose_w<<<dim3(64,64), tb, 0, stream>>>(wk, wqkvt + 2048*2048,  D_MODEL, D_MODEL);
  k_transpose_w<<<dim3(64,64), tb, 0, stream>>>(wv, wqkvt + 2*2048*2048,D_MODEL, D_MODEL);
  k_transpose_w<<<dim3(64,64), tb, 0, stream>>>(wo, wot, D_MODEL, D_MODEL);
  k_transpose_w<<<dim3(DFF/32,64), tb, 0, stream>>>(w1, w1t, D_MODEL, DFF);
  k_transpose_w<<<dim3(DFF/32,64), tb, 0, stream>>>(w3, w3t, D_MODEL, DFF);
  k_transpose_w<<<dim3(64,DFF/32), tb, 0, stream>>>(w2, w2t, DFF, D_MODEL);
  k_concat3<<<24, 256, 0, stream>>>(bq, bk, bv, bqkv);

  k_rmsnorm<<<MTOK, 256, 0, stream>>>(x, g1, bufA);
  // fused QKV GEMM: M=4096, N=6144, K=2048
  k_gemm_bt<0><<<(DQKV/128)*(MTOK/128), 256, 0, stream>>>(bufA, wqkvt, bqkv, nullptr, nullptr, qkv, MTOK, DQKV, D_MODEL);
  k_transpose_v<<<dim3(SS/32, 128), tb, 0, stream>>>(qkv + 4096, vtb, DQKV);
  k_attn<<<dim3(SS/64, BB*NHEADS), 256, 0, stream>>>(qkv, qkv + 2048, vtb, bufA, DQKV);
  k_gemm_bt<1><<<16*32, 256, 0, stream>>>(bufA, wot, bo, x, nullptr, out, MTOK, D_MODEL, D_MODEL);
  k_rmsnorm<<<MTOK, 256, 0, stream>>>(out, g2, bufA);
  k_gemm_bt<2><<<(DFF/128)*32, 256, 0, stream>>>(bufA, w1t, nullptr, nullptr, nullptr, h1, MTOK, DFF, D_MODEL);
  k_gemm_bt<4><<<(DFF/128)*32, 256, 0, stream>>>(bufA, w3t, nullptr, nullptr, h1, h1, MTOK, DFF, D_MODEL);
  k_gemm_bt<3><<<16*32, 256, 0, stream>>>(h1, w2t, nullptr, out, nullptr, out, MTOK, D_MODEL, DFF);
}